// Round 12
// baseline (339.138 us; speedup 1.0000x reference)
//
#include <hip/hip_runtime.h>
#include <hip/hip_bf16.h>
#include <math.h>

#define B_  256
#define N_  80
#define C_  1024
#define CO_ 1024

typedef __hip_bfloat16 bf16;
using bf16x8 = __attribute__((ext_vector_type(8))) short;   // 8 bf16 = 4 VGPRs
using f32x4  = __attribute__((ext_vector_type(4))) float;

__device__ __forceinline__ float leaky(float v){ return v >= 0.f ? v : 0.2f * v; }
__device__ __forceinline__ float sigmoidf_(float v){ return 1.f / (1.f + __expf(-v)); }

__device__ __forceinline__ void gll16(const void* g, void* l){
    __builtin_amdgcn_global_load_lds(
        (const __attribute__((address_space(1))) void*)g,
        (__attribute__((address_space(3))) void*)l, 16, 0, 0);
}

// ---------------- K0: transpose+convert both weights: WT[n][k]=bf16(W[k][n]) --
__global__ __launch_bounds__(256) void k_convT2(const float* __restrict__ W0, const float* __restrict__ W1,
                                                bf16* __restrict__ T0, bf16* __restrict__ T1){
    __shared__ float t[32][33];
    const float* W = blockIdx.z ? W1 : W0;
    bf16* WT = blockIdx.z ? T1 : T0;
    int k0 = blockIdx.y * 32, n0 = blockIdx.x * 32;
    int tx = threadIdx.x & 31, ty = threadIdx.x >> 5;
    for (int i = ty; i < 32; i += 8) t[i][tx] = W[(size_t)(k0 + i) * 1024 + n0 + tx];
    __syncthreads();
    for (int i = ty; i < 32; i += 8)
        WT[(size_t)(n0 + i) * 1024 + k0 + tx] = __float2bfloat16(t[tx][i]);
}

// ---------------- K0b: plain casts ----------------
__global__ void k_cvt_ccw(const float* __restrict__ ccw, bf16* __restrict__ ccwb){
    int i = blockIdx.x * 256 + threadIdx.x;
    ccwb[i] = __float2bfloat16(ccw[i]);
}
__global__ void k_cvt4(const float* __restrict__ src, bf16* __restrict__ dst){
    int i = (blockIdx.x * 256 + threadIdx.x) * 4;
    float4 v = *(const float4*)(src + i);
    dst[i + 0] = __float2bfloat16(v.x);
    dst[i + 1] = __float2bfloat16(v.y);
    dst[i + 2] = __float2bfloat16(v.z);
    dst[i + 3] = __float2bfloat16(v.w);
}

// ---------------- K1: adj_s (bf16, [80][88] padded rows) ----------------
__global__ void k_adj(const float* __restrict__ A, bf16* __restrict__ adjb){
    __shared__ float d[N_];
    int t = threadIdx.x;
    if (t < N_){
        float s = 0.f;
        for (int j = 0; j < N_; j++) s += A[t * N_ + j];
        d[t] = rsqrtf(s);
    }
    __syncthreads();
    for (int idx = t; idx < N_ * N_; idx += 256){
        int i = idx / N_, j = idx - i * N_;
        adjb[i * 88 + j] = __float2bfloat16(d[i] * A[j * N_ + i] * d[j]);
    }
}

// ---------------- K2: h1 = bf16(leaky(adj_s @ x[b])) via MFMA ----------------
__global__ __launch_bounds__(128) void k_prop_static(const float* __restrict__ xsrc,
                                                     const bf16* __restrict__ Ag,
                                                     bf16* __restrict__ H){
    __shared__ bf16 Btl[128 * 88];
    __shared__ bf16 Al [80 * 88];
    int b = blockIdx.x, c0 = blockIdx.y * 128, tid = threadIdx.x;
    int wave = tid >> 6, lane = tid & 63;
    int l15 = lane & 15, hi = lane >> 4;

    #pragma unroll
    for (int k = 0; k < 7; k++){
        int cb = k * 128 + wave * 64;
        if (cb + lane < 880)
            gll16(Ag + (size_t)(cb + lane) * 8, Al + (size_t)cb * 8);
    }
    {
        size_t rowbase = (size_t)b * 81920 + c0 + tid;
        #pragma unroll 8
        for (int m = 0; m < 80; m++)
            Btl[tid * 88 + m] = __float2bfloat16(xsrc[rowbase + (size_t)m * 1024]);
    }
    __syncthreads();

    f32x4 acc[5][4];
    #pragma unroll
    for (int i = 0; i < 5; i++)
        #pragma unroll
        for (int j = 0; j < 4; j++) acc[i][j] = (f32x4){0.f, 0.f, 0.f, 0.f};

    #pragma unroll
    for (int ks = 0; ks < 3; ks++){
        bf16x8 a[5], bv[4];
        if (ks < 2){
            int k0 = ks * 32;
            #pragma unroll
            for (int i = 0; i < 5; i++)
                a[i] = *(const bf16x8*)(Al + (i * 16 + l15) * 88 + k0 + hi * 8);
            #pragma unroll
            for (int j = 0; j < 4; j++)
                bv[j] = *(const bf16x8*)(Btl + (wave * 64 + j * 16 + l15) * 88 + k0 + hi * 8);
        } else {
            int koff = (hi < 2) ? 64 + hi * 8 : 0;
            #pragma unroll
            for (int i = 0; i < 5; i++){
                bf16x8 v = *(const bf16x8*)(Al + (i * 16 + l15) * 88 + koff);
                if (hi >= 2) v = 0;
                a[i] = v;
            }
            #pragma unroll
            for (int j = 0; j < 4; j++){
                bf16x8 v = *(const bf16x8*)(Btl + (wave * 64 + j * 16 + l15) * 88 + koff);
                if (hi >= 2) v = 0;
                bv[j] = v;
            }
        }
        #pragma unroll
        for (int i = 0; i < 5; i++)
            #pragma unroll
            for (int j = 0; j < 4; j++)
                acc[i][j] = __builtin_amdgcn_mfma_f32_16x16x32_bf16(a[i], bv[j], acc[i][j], 0, 0, 0);
    }

    #pragma unroll
    for (int i = 0; i < 5; i++){
        #pragma unroll
        for (int r = 0; r < 4; r++){
            int orow = i * 16 + hi * 4 + r;
            #pragma unroll
            for (int j = 0; j < 4; j++){
                int ocol = c0 + wave * 64 + j * 16 + l15;
                H[(size_t)b * 81920 + (size_t)orow * 1024 + ocol] =
                    __float2bfloat16(leaky(acc[i][j][r]));
            }
        }
    }
}

// ---------------- K3/K13: 256x256 MFMA GEMM, BK=32, 3-buffer stage-2-ahead ---
// 8 waves (2Mx4N), per-wave out 128x64 at (wm*128, wn*64).
// Half-tiles (128 rows x 32k, 8KB, 1 gll16/thread): 0=A[0:128) 1=A[128:256)
// 2=B[0:128) 3=B[128:256). Phase p of kt stages HT_p(kt+2) into buf (kt+2)%3
// (never the read buffer). One {vmcnt(4); barrier} per K-tile boundary:
// drains kt+1's 4 loads (issued during kt-1, 4-8 phases of cover), keeps
// kt+2's 4 in flight. Tail waits vmcnt(0). Swizzle = r9's proven pattern.
// Grid 320 = 8 XCD x (10 row-tiles x 4 col-tiles), bijective.
template<int EPI>
__global__ __launch_bounds__(512, 1) void k_gemm_256(const bf16* __restrict__ Abf,
                                                     const bf16* __restrict__ WT,
                                                     const float* __restrict__ Res,
                                                     void* __restrict__ Outv){
    __shared__ alignas(16) bf16 As[3][256 * 32];   // 48 KB
    __shared__ alignas(16) bf16 Bs[3][256 * 32];   // 48 KB
    const int K = 1024;
    const int NT = 32;                    // K-tiles of BK=32
    int tid = threadIdx.x;
    int wave = tid >> 6, lane = tid & 63;
    int l15 = lane & 15, hi = lane >> 4;
    int wm = wave >> 2, wn = wave & 3;

    int bid = blockIdx.x;
    int xcd = bid & 7, idx = bid >> 3;
    int row0 = (xcd * 10 + (idx >> 2)) * 256;
    int col0 = (idx & 3) * 256;

    // staging: thread t -> chunk t of each half-tile: row sr=t>>2, slot t&3,
    // source k-slot pre-swizzled sq = (t&3) ^ ((t>>3)&3)  [= slot ^ (row>>1)&3]
    int sr = tid >> 2;
    int sq = (tid & 3) ^ ((tid >> 3) & 3);
    int wbase = wave * 512;               // elements; gll16 lane adds 16B each

    int soff = (hi ^ ((l15 >> 1) & 3)) * 8;   // read slot (elements); all row
                                              // bases are 0 mod 8 -> key = (l15>>1)&3

    f32x4 acc[8][4];
    #pragma unroll
    for (int i = 0; i < 8; i++)
        #pragma unroll
        for (int j = 0; j < 4; j++) acc[i][j] = (f32x4){0.f, 0.f, 0.f, 0.f};

    auto STAGE_HT = [&](int kt, int buf, int ht){
        const bf16* srcb;
        bf16* dst;
        if      (ht == 0){ srcb = Abf + (size_t)(row0 + sr) * K;       dst = &As[buf][0];    }
        else if (ht == 1){ srcb = Abf + (size_t)(row0 + 128 + sr) * K; dst = &As[buf][4096]; }
        else if (ht == 2){ srcb = WT  + (size_t)(col0 + sr) * K;       dst = &Bs[buf][0];    }
        else             { srcb = WT  + (size_t)(col0 + 128 + sr) * K; dst = &Bs[buf][4096]; }
        gll16(srcb + kt * 32 + sq * 8, dst + wbase);
    };

    // prologue: stage kt=0 (buf0) and kt=1 (buf1); drain kt0, keep kt1 in flight
    #pragma unroll
    for (int ht = 0; ht < 4; ht++) STAGE_HT(0, 0, ht);
    #pragma unroll
    for (int ht = 0; ht < 4; ht++) STAGE_HT(1, 1, ht);
    asm volatile("s_waitcnt vmcnt(4)" ::: "memory");
    __builtin_amdgcn_s_barrier();

    int buf = 0, sbuf = 2;                // read buffer, stage buffer (kt+2)
    for (int kt = 0; kt < NT; ++kt){
        const bf16* SA = &As[buf][0];
        const bf16* SB = &Bs[buf][0];
        bool st = (kt + 2 < NT);
        bf16x8 a[4], b0[2], b1[2];

        // ---- ph0: quadrant (rows-lo x cols-lo)
        if (st) STAGE_HT(kt + 2, sbuf, 0);
        #pragma unroll
        for (int i = 0; i < 4; i++)
            a[i] = *(const bf16x8*)(SA + (wm * 128 + i * 16 + l15) * 32 + soff);
        #pragma unroll
        for (int j = 0; j < 2; j++)
            b0[j] = *(const bf16x8*)(SB + (wn * 64 + j * 16 + l15) * 32 + soff);
        __builtin_amdgcn_s_setprio(1);
        #pragma unroll
        for (int i = 0; i < 4; i++)
            #pragma unroll
            for (int j = 0; j < 2; j++)
                acc[i][j] = __builtin_amdgcn_mfma_f32_16x16x32_bf16(a[i], b0[j], acc[i][j], 0, 0, 0);
        __builtin_amdgcn_s_setprio(0);

        // ---- ph1: (rows-lo x cols-hi)
        if (st) STAGE_HT(kt + 2, sbuf, 1);
        #pragma unroll
        for (int j = 0; j < 2; j++)
            b1[j] = *(const bf16x8*)(SB + (wn * 64 + 32 + j * 16 + l15) * 32 + soff);
        __builtin_amdgcn_s_setprio(1);
        #pragma unroll
        for (int i = 0; i < 4; i++)
            #pragma unroll
            for (int j = 0; j < 2; j++)
                acc[i][2 + j] = __builtin_amdgcn_mfma_f32_16x16x32_bf16(a[i], b1[j], acc[i][2 + j], 0, 0, 0);
        __builtin_amdgcn_s_setprio(0);

        // ---- ph2: (rows-hi x cols-hi)  (a[] reused for rows-hi)
        if (st) STAGE_HT(kt + 2, sbuf, 2);
        #pragma unroll
        for (int i = 0; i < 4; i++)
            a[i] = *(const bf16x8*)(SA + (wm * 128 + 64 + i * 16 + l15) * 32 + soff);
        __builtin_amdgcn_s_setprio(1);
        #pragma unroll
        for (int i = 0; i < 4; i++)
            #pragma unroll
            for (int j = 0; j < 2; j++)
                acc[4 + i][2 + j] = __builtin_amdgcn_mfma_f32_16x16x32_bf16(a[i], b1[j], acc[4 + i][2 + j], 0, 0, 0);
        __builtin_amdgcn_s_setprio(0);

        // ---- ph3: (rows-hi x cols-lo)
        if (st) STAGE_HT(kt + 2, sbuf, 3);
        __builtin_amdgcn_s_setprio(1);
        #pragma unroll
        for (int i = 0; i < 4; i++)
            #pragma unroll
            for (int j = 0; j < 2; j++)
                acc[4 + i][j] = __builtin_amdgcn_mfma_f32_16x16x32_bf16(a[i], b0[j], acc[4 + i][j], 0, 0, 0);
        __builtin_amdgcn_s_setprio(0);

        // ---- K-tile boundary: drain kt+1's loads, publish to all waves
        if (st) asm volatile("s_waitcnt vmcnt(4)" ::: "memory");
        else    asm volatile("s_waitcnt vmcnt(0)" ::: "memory");
        if (kt + 1 < NT) __builtin_amdgcn_s_barrier();

        buf  = (buf  == 2) ? 0 : buf  + 1;
        sbuf = (sbuf == 2) ? 0 : sbuf + 1;
    }

    int orow = row0 + wm * 128 + hi * 4;
    int ocol = col0 + wn * 64 + l15;
    #pragma unroll
    for (int i = 0; i < 8; i++){
        #pragma unroll
        for (int r = 0; r < 4; r++){
            int rr = orow + i * 16 + r;
            #pragma unroll
            for (int j = 0; j < 4; j++){
                size_t o = (size_t)rr * 1024 + ocol + j * 16;
                float v = acc[i][j][r];
                if (EPI == 0) ((bf16*)Outv)[o] = __float2bfloat16(v + Res[o]);
                else          ((float*)Outv)[o] = leaky(v);
            }
        }
    }
}

// ---------------- K5: GLB1[b][co] = GLB0b @ cgw^T + cgb, bf16 MFMA -----------
__global__ __launch_bounds__(256) void k_gemm_glb(const bf16* __restrict__ Abf,
                                                  const bf16* __restrict__ Bw,
                                                  const float* __restrict__ bias,
                                                  float* __restrict__ Out){
    __shared__ alignas(16) bf16 As[3][128 * 32];
    __shared__ alignas(16) bf16 Bs[3][128 * 32];
    const int K = 1024;
    const int NT = 32;
    int tid = threadIdx.x;
    int wave = tid >> 6, lane = tid & 63;
    int l15 = lane & 15, hi = lane >> 4;

    int row0 = (blockIdx.x >> 3) * 128;
    int col0 = (blockIdx.x & 7) * 128;

    int sr = tid >> 2;
    int sq = (tid & 3) ^ ((tid >> 3) & 3);
    const bf16* gA = Abf + (size_t)(row0 + sr) * K + sq * 8;
    const bf16* gB = Bw  + (size_t)(col0 + sr) * K + sq * 8;

    int wr = (wave >> 1) * 64, wc = (wave & 1) * 64;
    int soff = (hi ^ ((l15 >> 1) & 3)) * 8;

    f32x4 acc[4][4];
    #pragma unroll
    for (int i = 0; i < 4; i++)
        #pragma unroll
        for (int j = 0; j < 4; j++) acc[i][j] = (f32x4){0.f, 0.f, 0.f, 0.f};

    auto STAGE = [&](int t){
        int buf = t % 3;
        int k0 = t * 32;
        bf16* da = &As[buf][wave * 512];
        bf16* db = &Bs[buf][wave * 512];
        gll16(gA + k0, da);
        gll16(gA + (size_t)64 * K + k0, da + 2048);
        gll16(gB + k0, db);
        gll16(gB + (size_t)64 * K + k0, db + 2048);
    };

    STAGE(0);
    STAGE(1);
    for (int t = 0; t < NT; ++t){
        if (t == NT - 1) asm volatile("s_waitcnt vmcnt(0)" ::: "memory");
        else             asm volatile("s_waitcnt vmcnt(4)" ::: "memory");
        __builtin_amdgcn_s_barrier();
        if (t + 2 < NT) STAGE(t + 2);
        int buf = t % 3;
        const bf16* pa = &As[buf][0] + (wr + l15) * 32 + soff;
        const bf16* pb = &Bs[buf][0] + (wc + l15) * 32 + soff;
        bf16x8 a[4], b[4];
        #pragma unroll
        for (int i = 0; i < 4; i++) a[i] = *(const bf16x8*)(pa + i * 512);
        #pragma unroll
        for (int j = 0; j < 4; j++) b[j] = *(const bf16x8*)(pb + j * 512);
        #pragma unroll
        for (int i = 0; i < 4; i++)
            #pragma unroll
            for (int j = 0; j < 4; j++)
                acc[i][j] = __builtin_amdgcn_mfma_f32_16x16x32_bf16(a[i], b[j], acc[i][j], 0, 0, 0);
    }

    int orow = row0 + wr + hi * 4;
    int ocol = col0 + wc + l15;
    #pragma unroll
    for (int i = 0; i < 4; i++){
        #pragma unroll
        for (int r = 0; r < 4; r++){
            int rr = orow + i * 16 + r;
            #pragma unroll
            for (int j = 0; j < 4; j++){
                int cl = ocol + j * 16;
                Out[(size_t)rr * 1024 + cl] = acc[i][j][r] + bias[cl];
            }
        }
    }
}

// ---------------- K4: glb0b[b,c] = bf16(mean_n x2b[b,n,c]) ----------------
__global__ __launch_bounds__(128) void k_pool(const bf16* __restrict__ X2b, bf16* __restrict__ glb0b){
    int b = blockIdx.x, c8 = threadIdx.x * 8;
    const bf16* p = X2b + (size_t)b * 81920 + c8;
    float s[8] = {0.f,0.f,0.f,0.f,0.f,0.f,0.f,0.f};
    #pragma unroll 8
    for (int nn = 0; nn < N_; nn++){
        union { bf16x8 v; bf16 e[8]; } u;
        u.v = *(const bf16x8*)(p + (size_t)nn * 1024);
        #pragma unroll
        for (int k = 0; k < 8; k++) s[k] += __bfloat162float(u.e[k]);
    }
    #pragma unroll
    for (int k = 0; k < 8; k++)
        glb0b[b * C_ + c8 + k] = __float2bfloat16(s[k] * (1.f / N_));
}

// ---------------- K6: BN stats over batch (high-TLP) ----------------
__global__ __launch_bounds__(256) void k_bnstat(const float* __restrict__ g, float* __restrict__ mu,
                                                float* __restrict__ rstd){
    __shared__ float rs[8][32], rs2[8][32];
    int tid = threadIdx.x;
    int c = blockIdx.x * 32 + (tid & 31);
    int grp = tid >> 5;
    float s = 0.f, s2 = 0.f;
    for (int bb = 0; bb < 32; bb++){
        float v = g[(size_t)(grp * 32 + bb) * 1024 + c];
        s += v; s2 += v * v;
    }
    rs[grp][tid & 31] = s;
    rs2[grp][tid & 31] = s2;
    __syncthreads();
    if (tid < 32){
        float S = 0.f, S2 = 0.f;
        #pragma unroll
        for (int q = 0; q < 8; q++){ S += rs[q][tid]; S2 += rs2[q][tid]; }
        float m = S * (1.f / B_);
        float var = S2 * (1.f / B_) - m * m;
        int cc = blockIdx.x * 32 + tid;
        mu[cc] = m;
        rstd[cc] = rsqrtf(var + 1e-5f);
    }
}

// ---------------- K7: glb2b = bf16(leaky(BN(glb1))) ----------------
__global__ void k_bnapply(const float* __restrict__ g, const float* __restrict__ mu,
                          const float* __restrict__ rstd, const float* __restrict__ gamma,
                          const float* __restrict__ beta, bf16* __restrict__ o){
    int i = blockIdx.x * 256 + threadIdx.x;
    int c = i & (C_ - 1);
    float v = (g[i] - mu[c]) * rstd[c] * gamma[c] + beta[c];
    o[i] = __float2bfloat16(leaky(v));
}

// ---------------- K9: MEGA-FUSED dyn + loss + adj + dynamic propagation -----
__global__ __launch_bounds__(512) void k_dyn_prop(const bf16* __restrict__ X2b,
                                                  const bf16* __restrict__ ccwb,
                                                  const bf16* __restrict__ glb2b,
                                                  const float* __restrict__ ccb,
                                                  const float* __restrict__ out1,
                                                  bf16* __restrict__ H,
                                                  float* __restrict__ lossp){
    __shared__ char uSb[80 * 81 * 4];       // S f32 [80][81]  /  Btl bf16 [128][90]
    __shared__ bf16 ADJ[80 * 90];
    __shared__ float di_s[80], o1s[80], dd[80];
    float* S = (float*)uSb;
    bf16* Btl = (bf16*)uSb;
    int b = blockIdx.x, tid = threadIdx.x;
    int wave = tid >> 6, lane = tid & 63;
    int l15 = lane & 15, hi = lane >> 4;

    if (wave < 5){
        const bf16* arow = ccwb + (size_t)(wave * 16 + l15) * 2048 + hi * 8;
        const bf16* gG = glb2b + (size_t)b * 1024 + hi * 8;
        const bf16* gX = X2b + (size_t)b * 81920 + hi * 8;
        f32x4 acc[5];
        #pragma unroll
        for (int j = 0; j < 5; j++) acc[j] = (f32x4){0.f, 0.f, 0.f, 0.f};
        #pragma unroll 8
        for (int k0 = 0; k0 < 1024; k0 += 32){
            bf16x8 a = *(const bf16x8*)(arow + k0);
            bf16x8 g = *(const bf16x8*)(gG + k0);
            #pragma unroll
            for (int j = 0; j < 5; j++)
                acc[j] = __builtin_amdgcn_mfma_f32_16x16x32_bf16(a, g, acc[j], 0, 0, 0);
        }
        #pragma unroll 4
        for (int k0 = 0; k0 < 1024; k0 += 32){
            bf16x8 a = *(const bf16x8*)(arow + 1024 + k0);
            #pragma unroll
            for (int j = 0; j < 5; j++){
                bf16x8 bv = *(const bf16x8*)(gX + (size_t)(j * 16 + l15) * 1024 + k0);
                acc[j] = __builtin_amdgcn_mfma_f32_16x16x32_bf16(a, bv, acc[j], 0, 0, 0);
            }
        }
        #pragma unroll
        for (int r = 0; r < 4; r++){
            int n = wave * 16 + hi * 4 + r;
            float cb = ccb[n];
            #pragma unroll
            for (int j = 0; j < 5; j++)
                S[n * 81 + j * 16 + l15] = sigmoidf_(acc[j][r] + cb);
        }
    }
    __syncthreads();
    if (tid < 80){
        float rsum = 0.f;
        #pragma unroll 8
        for (int m = 0; m < 80; m++) rsum += S[tid * 81 + m];
        di_s[tid] = rsqrtf(rsum);
        o1s[tid] = sigmoidf_(out1[b * 80 + tid]);
    }
    __syncthreads();
    if (tid < 80){
        float cs = 0.f;
        #pragma unroll 8
        for (int n = 0; n < 80; n++) cs += o1s[n] * S[n * 81 + tid];
        float diff = o1s[tid] - cs * (1.f / 80.f);
        dd[tid] = diff * diff;
    }
    __syncthreads();
    for (int idx = tid; idx < 6400; idx += 512){
        int n = idx / 80, m = idx - n * 80;
        ADJ[n * 90 + m] = __float2bfloat16(di_s[n] * S[m * 81 + n] * di_s[m]);
    }
    if (tid == 0){
        float s = 0.f;
        for (int m = 0; m < 80; m++) s += dd[m];
        lossp[b] = sqrtf(s);
    }
    for (int c0 = 0; c0 < 1024; c0 += 128){
        __syncthreads();
        {
            int cc = tid & 127, g = tid >> 7;
            const bf16* src = X2b + (size_t)b * 81920 + c0 + cc;
            #pragma unroll 5
            for (int m = g * 20; m < g * 20 + 20; m++)
                Btl[cc * 90 + m] = src[(size_t)m * 1024];
        }
        __syncthreads();
        f32x4 pacc[5];
        #pragma unroll
        for (int i = 0; i < 5; i++) pacc[i] = (f32x4){0.f, 0.f, 0.f, 0.f};
        #pragma unroll
        for (int ks = 0; ks < 3; ks++){
            int koff = (ks < 2) ? ks * 32 + hi * 8 : ((hi < 2) ? 64 + hi * 8 : 0);
            bool dead = (ks == 2) && (hi >= 2);
            bf16x8 bv = *(const bf16x8*)(Btl + (wave * 16 + l15) * 90 + koff);
            if (dead) bv = 0;
            #pragma unroll
            for (int i = 0; i < 5; i++){
                bf16x8 a = *(const bf16x8*)(ADJ + (i * 16 + l15) * 90 + koff);
                if (dead) a = 0;
                pacc[i] = __builtin_amdgcn_mfma_f32_16x16x32_bf16(a, bv, pacc[i], 0, 0, 0);
            }
        }
        #pragma unroll
        for (int i = 0; i < 5; i++){
            #pragma unroll
            for (int r = 0; r < 4; r++){
                int n = i * 16 + hi * 4 + r;
                int col = c0 + wave * 16 + l15;
                H[(size_t)b * 81920 + (size_t)n * 1024 + col] =
                    __float2bfloat16(leaky(pacc[i][r]));
            }
        }
    }
}

// ---------------- K11: loss = sum(lossp) ----------------
__global__ void k_lsum(const float* __restrict__ lossp, float* __restrict__ out_loss){
    float v = lossp[threadIdx.x];
    for (int off = 32; off; off >>= 1) v += __shfl_down(v, off);
    __shared__ float wsum[4];
    int lane = threadIdx.x & 63, w = threadIdx.x >> 6;
    if (lane == 0) wsum[w] = v;
    __syncthreads();
    if (threadIdx.x == 0) out_loss[0] = wsum[0] + wsum[1] + wsum[2] + wsum[3];
}

extern "C" void kernel_launch(void* const* d_in, const int* in_sizes, int n_in,
                              void* d_out, int out_size, void* d_ws, size_t ws_size,
                              hipStream_t stream) {
    const float* x     = (const float*)d_in[0];
    const float* out1  = (const float*)d_in[1];
    const float* A     = (const float*)d_in[2];
    const float* sw    = (const float*)d_in[3];
    const float* cgw   = (const float*)d_in[4];
    const float* cgb   = (const float*)d_in[5];
    const float* gamma = (const float*)d_in[6];
    const float* beta  = (const float*)d_in[7];
    const float* ccw   = (const float*)d_in[8];
    const float* ccb   = (const float*)d_in[9];
    const float* dw    = (const float*)d_in[10];
    float* out = (float*)d_out;

    const size_t XN = (size_t)B_ * N_ * C_;   // 20,971,520
    char* p = (char*)d_ws;
    bf16*  Hbf  = (bf16*)p;   p += XN * 2;               // 42 MB
    bf16*  X2b  = (bf16*)p;   p += XN * 2;               // 42 MB
    bf16*  SWT  = (bf16*)p;   p += (size_t)C_ * C_ * 2;  // 2 MB
    bf16*  DWT  = (bf16*)p;   p += (size_t)C_ * CO_ * 2; // 2 MB
    bf16*  CCWB = (bf16*)p;   p += (size_t)N_ * 2048 * 2;
    bf16*  CGWB = (bf16*)p;   p += (size_t)C_ * C_ * 2;  // 2 MB
    bf16*  ADJS = (bf16*)p;   p += (size_t)80 * 88 * 2;
    bf16*  GLB0 = (bf16*)p;   p += (size_t)B_ * C_ * 2;
    float* GLB1 = (float*)p;  p += (size_t)B_ * C_ * 4;
    bf16*  GLB2 = (bf16*)p;   p += (size_t)B_ * C_ * 2;
    float* MU   = (float*)p;  p += C_ * 4;
    float* RSTD = (float*)p;  p += C_ * 4;
    float* LOSSP= (float*)p;  p += B_ * 4;

    k_convT2<<<dim3(32, 32, 2), 256, 0, stream>>>(sw, dw, SWT, DWT);
    k_cvt_ccw<<<(N_ * 2048) / 256, 256, 0, stream>>>(ccw, CCWB);
    k_cvt4<<<(C_ * C_) / 1024, 256, 0, stream>>>(cgw, CGWB);
    k_adj<<<1, 256, 0, stream>>>(A, ADJS);
    k_prop_static<<<dim3(B_, 8), 128, 0, stream>>>(x, ADJS, Hbf);
    k_gemm_256<0><<<320, 512, 0, stream>>>(Hbf, SWT, x, X2b);
    k_pool<<<B_, 128, 0, stream>>>(X2b, GLB0);
    k_gemm_glb<<<16, 256, 0, stream>>>(GLB0, CGWB, cgb, GLB1);
    k_bnstat<<<32, 256, 0, stream>>>(GLB1, MU, RSTD);
    k_bnapply<<<(B_ * C_) / 256, 256, 0, stream>>>(GLB1, MU, RSTD, gamma, beta, GLB2);
    k_dyn_prop<<<B_, 512, 0, stream>>>(X2b, CCWB, GLB2, ccb, out1, Hbf, LOSSP);
    k_lsum<<<1, 256, 0, stream>>>(LOSSP, out + (size_t)B_ * N_ * CO_);
    k_gemm_256<1><<<320, 512, 0, stream>>>(Hbf, DWT, nullptr, out);
}

// Round 13
// 255.924 us; speedup vs baseline: 1.3252x; 1.3252x over previous
//
#include <hip/hip_runtime.h>
#include <hip/hip_bf16.h>
#include <math.h>

#define B_  256
#define N_  80
#define C_  1024
#define CO_ 1024

typedef __hip_bfloat16 bf16;
using bf16x8 = __attribute__((ext_vector_type(8))) short;   // 8 bf16 = 4 VGPRs
using f32x4  = __attribute__((ext_vector_type(4))) float;

__device__ __forceinline__ float leaky(float v){ return v >= 0.f ? v : 0.2f * v; }
__device__ __forceinline__ float sigmoidf_(float v){ return 1.f / (1.f + __expf(-v)); }

__device__ __forceinline__ void gll16(const void* g, void* l){
    __builtin_amdgcn_global_load_lds(
        (const __attribute__((address_space(1))) void*)g,
        (__attribute__((address_space(3))) void*)l, 16, 0, 0);
}

// ---------------- K0: transpose+convert both weights: WT[n][k]=bf16(W[k][n]) --
__global__ __launch_bounds__(256) void k_convT2(const float* __restrict__ W0, const float* __restrict__ W1,
                                                bf16* __restrict__ T0, bf16* __restrict__ T1){
    __shared__ float t[32][33];
    const float* W = blockIdx.z ? W1 : W0;
    bf16* WT = blockIdx.z ? T1 : T0;
    int k0 = blockIdx.y * 32, n0 = blockIdx.x * 32;
    int tx = threadIdx.x & 31, ty = threadIdx.x >> 5;
    for (int i = ty; i < 32; i += 8) t[i][tx] = W[(size_t)(k0 + i) * 1024 + n0 + tx];
    __syncthreads();
    for (int i = ty; i < 32; i += 8)
        WT[(size_t)(n0 + i) * 1024 + k0 + tx] = __float2bfloat16(t[tx][i]);
}

// ---------------- K0b: merged f32->bf16 casts (ccw then cgw), float4-wide ----
__global__ void k_cvt_all(const float* __restrict__ ccw, const float* __restrict__ cgw,
                          bf16* __restrict__ ccwb, bf16* __restrict__ cgwb){
    int q = blockIdx.x * 256 + threadIdx.x;      // float4 index
    const int NCC = (N_ * 2048) / 4;             // 40960
    const float* src; bf16* dst; int i;
    if (q < NCC){ src = ccw; dst = ccwb; i = q * 4; }
    else        { src = cgw; dst = cgwb; i = (q - NCC) * 4; }
    float4 v = *(const float4*)(src + i);
    dst[i + 0] = __float2bfloat16(v.x);
    dst[i + 1] = __float2bfloat16(v.y);
    dst[i + 2] = __float2bfloat16(v.z);
    dst[i + 3] = __float2bfloat16(v.w);
}

// ---------------- K1: adj_s (bf16, [80][88] padded rows) ----------------
__global__ void k_adj(const float* __restrict__ A, bf16* __restrict__ adjb){
    __shared__ float d[N_];
    int t = threadIdx.x;
    if (t < N_){
        float s = 0.f;
        for (int j = 0; j < N_; j++) s += A[t * N_ + j];
        d[t] = rsqrtf(s);
    }
    __syncthreads();
    for (int idx = t; idx < N_ * N_; idx += 256){
        int i = idx / N_, j = idx - i * N_;
        adjb[i * 88 + j] = __float2bfloat16(d[i] * A[j * N_ + i] * d[j]);
    }
}

// ---------------- K2: h1 = bf16(leaky(adj_s @ x[b])) via MFMA ----------------
__global__ __launch_bounds__(128) void k_prop_static(const float* __restrict__ xsrc,
                                                     const bf16* __restrict__ Ag,
                                                     bf16* __restrict__ H){
    __shared__ bf16 Btl[128 * 88];
    __shared__ bf16 Al [80 * 88];
    int b = blockIdx.x, c0 = blockIdx.y * 128, tid = threadIdx.x;
    int wave = tid >> 6, lane = tid & 63;
    int l15 = lane & 15, hi = lane >> 4;

    #pragma unroll
    for (int k = 0; k < 7; k++){
        int cb = k * 128 + wave * 64;
        if (cb + lane < 880)
            gll16(Ag + (size_t)(cb + lane) * 8, Al + (size_t)cb * 8);
    }
    {
        size_t rowbase = (size_t)b * 81920 + c0 + tid;
        #pragma unroll 8
        for (int m = 0; m < 80; m++)
            Btl[tid * 88 + m] = __float2bfloat16(xsrc[rowbase + (size_t)m * 1024]);
    }
    __syncthreads();

    f32x4 acc[5][4];
    #pragma unroll
    for (int i = 0; i < 5; i++)
        #pragma unroll
        for (int j = 0; j < 4; j++) acc[i][j] = (f32x4){0.f, 0.f, 0.f, 0.f};

    #pragma unroll
    for (int ks = 0; ks < 3; ks++){
        bf16x8 a[5], bv[4];
        if (ks < 2){
            int k0 = ks * 32;
            #pragma unroll
            for (int i = 0; i < 5; i++)
                a[i] = *(const bf16x8*)(Al + (i * 16 + l15) * 88 + k0 + hi * 8);
            #pragma unroll
            for (int j = 0; j < 4; j++)
                bv[j] = *(const bf16x8*)(Btl + (wave * 64 + j * 16 + l15) * 88 + k0 + hi * 8);
        } else {
            int koff = (hi < 2) ? 64 + hi * 8 : 0;
            #pragma unroll
            for (int i = 0; i < 5; i++){
                bf16x8 v = *(const bf16x8*)(Al + (i * 16 + l15) * 88 + koff);
                if (hi >= 2) v = 0;
                a[i] = v;
            }
            #pragma unroll
            for (int j = 0; j < 4; j++){
                bf16x8 v = *(const bf16x8*)(Btl + (wave * 64 + j * 16 + l15) * 88 + koff);
                if (hi >= 2) v = 0;
                bv[j] = v;
            }
        }
        #pragma unroll
        for (int i = 0; i < 5; i++)
            #pragma unroll
            for (int j = 0; j < 4; j++)
                acc[i][j] = __builtin_amdgcn_mfma_f32_16x16x32_bf16(a[i], bv[j], acc[i][j], 0, 0, 0);
    }

    #pragma unroll
    for (int i = 0; i < 5; i++){
        #pragma unroll
        for (int r = 0; r < 4; r++){
            int orow = i * 16 + hi * 4 + r;
            #pragma unroll
            for (int j = 0; j < 4; j++){
                int ocol = c0 + wave * 64 + j * 16 + l15;
                H[(size_t)b * 81920 + (size_t)orow * 1024 + ocol] =
                    __float2bfloat16(leaky(acc[i][j][r]));
            }
        }
    }
}

// ---------------- K3/K13: bf16 MFMA GEMM, A 3-buf / B 2-buf (r9, 69us) -------
template<int EPI>
__global__ __launch_bounds__(256, 4) void k_gemm_mfma(const bf16* __restrict__ Abf,
                                                      const bf16* __restrict__ WT,
                                                      const float* __restrict__ Res,
                                                      void* __restrict__ Outv){
    __shared__ alignas(16) bf16 As[3][128 * 32];
    __shared__ alignas(16) bf16 Bs[2][128 * 32];
    const int K = 1024;
    const int NT = 32;
    int tid = threadIdx.x;
    int wave = tid >> 6, lane = tid & 63;
    int l15 = lane & 15, hi = lane >> 4;

    int bid = blockIdx.x;
    int xcd = bid & 7, idx = bid >> 3;
    int row0 = (xcd * 20 + (idx >> 3)) * 128;
    int col0 = (idx & 7) * 128;

    int sr = tid >> 2;
    int sq = (tid & 3) ^ ((tid >> 3) & 3);
    const bf16* gA = Abf + (size_t)(row0 + sr) * K + sq * 8;
    const bf16* gB = WT  + (size_t)(col0 + sr) * K + sq * 8;

    int wr = (wave >> 1) * 64, wc = (wave & 1) * 64;
    int soff = (hi ^ ((l15 >> 1) & 3)) * 8;

    f32x4 acc[4][4];
    #pragma unroll
    for (int i = 0; i < 4; i++)
        #pragma unroll
        for (int j = 0; j < 4; j++) acc[i][j] = (f32x4){0.f, 0.f, 0.f, 0.f};

    auto STAGE_A = [&](int t){
        bf16* da = &As[t % 3][wave * 512];
        gll16(gA + t * 32, da);
        gll16(gA + (size_t)64 * K + t * 32, da + 2048);
    };
    auto STAGE_B = [&](int t){
        bf16* db = &Bs[t & 1][wave * 512];
        gll16(gB + t * 32, db);
        gll16(gB + (size_t)64 * K + t * 32, db + 2048);
    };

    STAGE_A(0); STAGE_B(0); STAGE_A(1);
    for (int t = 0; t < NT; ++t){
        if (t < NT - 1) asm volatile("s_waitcnt vmcnt(2)" ::: "memory");
        else            asm volatile("s_waitcnt vmcnt(0)" ::: "memory");
        __builtin_amdgcn_s_barrier();
        if (t + 1 < NT) STAGE_B(t + 1);
        if (t + 2 < NT) STAGE_A(t + 2);
        const bf16* pa = &As[t % 3][0] + (wr + l15) * 32 + soff;
        const bf16* pb = &Bs[t & 1][0] + (wc + l15) * 32 + soff;
        bf16x8 a[4], b[4];
        #pragma unroll
        for (int i = 0; i < 4; i++) a[i] = *(const bf16x8*)(pa + i * 512);
        #pragma unroll
        for (int j = 0; j < 4; j++) b[j] = *(const bf16x8*)(pb + j * 512);
        __builtin_amdgcn_s_setprio(1);
        #pragma unroll
        for (int i = 0; i < 4; i++)
            #pragma unroll
            for (int j = 0; j < 4; j++)
                acc[i][j] = __builtin_amdgcn_mfma_f32_16x16x32_bf16(a[i], b[j], acc[i][j], 0, 0, 0);
        __builtin_amdgcn_s_setprio(0);
    }

    int orow = row0 + wr + hi * 4;
    int ocol = col0 + wc + l15;
    #pragma unroll
    for (int i = 0; i < 4; i++){
        #pragma unroll
        for (int r = 0; r < 4; r++){
            int rr = orow + i * 16 + r;
            #pragma unroll
            for (int j = 0; j < 4; j++){
                size_t o = (size_t)rr * 1024 + ocol + j * 16;
                float v = acc[i][j][r];
                if (EPI == 0) ((bf16*)Outv)[o] = __float2bfloat16(v + Res[o]);
                else          ((float*)Outv)[o] = leaky(v);
            }
        }
    }
}

// ---------------- K5: GLB1P[kc] = GLB0b @ cgw^T (K-chunk kc), no bias --------
// Grid 64 = 2 row x 8 col x 4 K-chunks (256 K each, NT=8). Parts summed in BN.
__global__ __launch_bounds__(256) void k_gemm_glb(const bf16* __restrict__ Abf,
                                                  const bf16* __restrict__ Bw,
                                                  float* __restrict__ OutP){
    __shared__ alignas(16) bf16 As[3][128 * 32];
    __shared__ alignas(16) bf16 Bs[3][128 * 32];
    const int K = 1024;
    const int NT = 8;
    int tid = threadIdx.x;
    int wave = tid >> 6, lane = tid & 63;
    int l15 = lane & 15, hi = lane >> 4;

    int bid = blockIdx.x;
    int row0 = ((bid >> 3) & 1) * 128;
    int col0 = (bid & 7) * 128;
    int kc = bid >> 4;                       // 0..3
    int kbase = kc * 256;
    float* Out = OutP + (size_t)kc * 256 * 1024;

    int sr = tid >> 2;
    int sq = (tid & 3) ^ ((tid >> 3) & 3);
    const bf16* gA = Abf + (size_t)(row0 + sr) * K + kbase + sq * 8;
    const bf16* gB = Bw  + (size_t)(col0 + sr) * K + kbase + sq * 8;

    int wr = (wave >> 1) * 64, wc = (wave & 1) * 64;
    int soff = (hi ^ ((l15 >> 1) & 3)) * 8;

    f32x4 acc[4][4];
    #pragma unroll
    for (int i = 0; i < 4; i++)
        #pragma unroll
        for (int j = 0; j < 4; j++) acc[i][j] = (f32x4){0.f, 0.f, 0.f, 0.f};

    auto STAGE = [&](int t){
        int buf = t % 3;
        int k0 = t * 32;
        bf16* da = &As[buf][wave * 512];
        bf16* db = &Bs[buf][wave * 512];
        gll16(gA + k0, da);
        gll16(gA + (size_t)64 * K + k0, da + 2048);
        gll16(gB + k0, db);
        gll16(gB + (size_t)64 * K + k0, db + 2048);
    };

    STAGE(0);
    STAGE(1);
    for (int t = 0; t < NT; ++t){
        if (t == NT - 1) asm volatile("s_waitcnt vmcnt(0)" ::: "memory");
        else             asm volatile("s_waitcnt vmcnt(4)" ::: "memory");
        __builtin_amdgcn_s_barrier();
        if (t + 2 < NT) STAGE(t + 2);
        int buf = t % 3;
        const bf16* pa = &As[buf][0] + (wr + l15) * 32 + soff;
        const bf16* pb = &Bs[buf][0] + (wc + l15) * 32 + soff;
        bf16x8 a[4], b[4];
        #pragma unroll
        for (int i = 0; i < 4; i++) a[i] = *(const bf16x8*)(pa + i * 512);
        #pragma unroll
        for (int j = 0; j < 4; j++) b[j] = *(const bf16x8*)(pb + j * 512);
        #pragma unroll
        for (int i = 0; i < 4; i++)
            #pragma unroll
            for (int j = 0; j < 4; j++)
                acc[i][j] = __builtin_amdgcn_mfma_f32_16x16x32_bf16(a[i], b[j], acc[i][j], 0, 0, 0);
    }

    int orow = row0 + wr + hi * 4;
    int ocol = col0 + wc + l15;
    #pragma unroll
    for (int i = 0; i < 4; i++){
        #pragma unroll
        for (int r = 0; r < 4; r++){
            int rr = orow + i * 16 + r;
            #pragma unroll
            for (int j = 0; j < 4; j++)
                Out[(size_t)rr * 1024 + ocol + j * 16] = acc[i][j][r];
        }
    }
}

// ---------------- K4: glb0b[b,c] = bf16(mean_n x2b[b,n,c]) ----------------
__global__ __launch_bounds__(128) void k_pool(const bf16* __restrict__ X2b, bf16* __restrict__ glb0b){
    int b = blockIdx.x, c8 = threadIdx.x * 8;
    const bf16* p = X2b + (size_t)b * 81920 + c8;
    float s[8] = {0.f,0.f,0.f,0.f,0.f,0.f,0.f,0.f};
    #pragma unroll 8
    for (int nn = 0; nn < N_; nn++){
        union { bf16x8 v; bf16 e[8]; } u;
        u.v = *(const bf16x8*)(p + (size_t)nn * 1024);
        #pragma unroll
        for (int k = 0; k < 8; k++) s[k] += __bfloat162float(u.e[k]);
    }
    #pragma unroll
    for (int k = 0; k < 8; k++)
        glb0b[b * C_ + c8 + k] = __float2bfloat16(s[k] * (1.f / N_));
}

// ---------------- K6: BN stats over batch (sums 4 K-parts) ----------------
__global__ __launch_bounds__(256) void k_bnstat(const float* __restrict__ gP, float* __restrict__ mu,
                                                float* __restrict__ rstd){
    __shared__ float rs[8][32], rs2[8][32];
    int tid = threadIdx.x;
    int c = blockIdx.x * 32 + (tid & 31);
    int grp = tid >> 5;
    float s = 0.f, s2 = 0.f;
    for (int bb = 0; bb < 32; bb++){
        size_t o = (size_t)(grp * 32 + bb) * 1024 + c;
        float v = gP[o] + gP[262144 + o] + gP[524288 + o] + gP[786432 + o];
        s += v; s2 += v * v;
    }
    rs[grp][tid & 31] = s;
    rs2[grp][tid & 31] = s2;
    __syncthreads();
    if (tid < 32){
        float S = 0.f, S2 = 0.f;
        #pragma unroll
        for (int q = 0; q < 8; q++){ S += rs[q][tid]; S2 += rs2[q][tid]; }
        float m = S * (1.f / B_);
        float var = S2 * (1.f / B_) - m * m;
        int cc = blockIdx.x * 32 + tid;
        mu[cc] = m;
        rstd[cc] = rsqrtf(var + 1e-5f);
    }
}

// ---------------- K7: glb2b = bf16(leaky(BN(sum of parts))) ----------------
__global__ void k_bnapply(const float* __restrict__ gP, const float* __restrict__ mu,
                          const float* __restrict__ rstd, const float* __restrict__ gamma,
                          const float* __restrict__ beta, bf16* __restrict__ o){
    int i = blockIdx.x * 256 + threadIdx.x;
    int c = i & (C_ - 1);
    float g = gP[i] + gP[262144 + i] + gP[524288 + i] + gP[786432 + i];
    float v = (g - mu[c]) * rstd[c] * gamma[c] + beta[c];
    o[i] = __float2bfloat16(leaky(v));
}

// ---------------- K9: MEGA-FUSED dyn + loss + adj + dynamic propagation -----
__global__ __launch_bounds__(512) void k_dyn_prop(const bf16* __restrict__ X2b,
                                                  const bf16* __restrict__ ccwb,
                                                  const bf16* __restrict__ glb2b,
                                                  const float* __restrict__ ccb,
                                                  const float* __restrict__ out1,
                                                  bf16* __restrict__ H,
                                                  float* __restrict__ lossp){
    __shared__ char uSb[80 * 81 * 4];       // S f32 [80][81]  /  Btl bf16 [128][90]
    __shared__ bf16 ADJ[80 * 90];
    __shared__ float di_s[80], o1s[80], dd[80];
    float* S = (float*)uSb;
    bf16* Btl = (bf16*)uSb;
    int b = blockIdx.x, tid = threadIdx.x;
    int wave = tid >> 6, lane = tid & 63;
    int l15 = lane & 15, hi = lane >> 4;

    if (wave < 5){
        const bf16* arow = ccwb + (size_t)(wave * 16 + l15) * 2048 + hi * 8;
        const bf16* gG = glb2b + (size_t)b * 1024 + hi * 8;
        const bf16* gX = X2b + (size_t)b * 81920 + hi * 8;
        f32x4 acc[5];
        #pragma unroll
        for (int j = 0; j < 5; j++) acc[j] = (f32x4){0.f, 0.f, 0.f, 0.f};
        #pragma unroll 8
        for (int k0 = 0; k0 < 1024; k0 += 32){
            bf16x8 a = *(const bf16x8*)(arow + k0);
            bf16x8 g = *(const bf16x8*)(gG + k0);
            #pragma unroll
            for (int j = 0; j < 5; j++)
                acc[j] = __builtin_amdgcn_mfma_f32_16x16x32_bf16(a, g, acc[j], 0, 0, 0);
        }
        #pragma unroll 4
        for (int k0 = 0; k0 < 1024; k0 += 32){
            bf16x8 a = *(const bf16x8*)(arow + 1024 + k0);
            #pragma unroll
            for (int j = 0; j < 5; j++){
                bf16x8 bv = *(const bf16x8*)(gX + (size_t)(j * 16 + l15) * 1024 + k0);
                acc[j] = __builtin_amdgcn_mfma_f32_16x16x32_bf16(a, bv, acc[j], 0, 0, 0);
            }
        }
        #pragma unroll
        for (int r = 0; r < 4; r++){
            int n = wave * 16 + hi * 4 + r;
            float cb = ccb[n];
            #pragma unroll
            for (int j = 0; j < 5; j++)
                S[n * 81 + j * 16 + l15] = sigmoidf_(acc[j][r] + cb);
        }
    }
    __syncthreads();
    if (tid < 80){
        float rsum = 0.f;
        #pragma unroll 8
        for (int m = 0; m < 80; m++) rsum += S[tid * 81 + m];
        di_s[tid] = rsqrtf(rsum);
        o1s[tid] = sigmoidf_(out1[b * 80 + tid]);
    }
    __syncthreads();
    if (tid < 80){
        float cs = 0.f;
        #pragma unroll 8
        for (int n = 0; n < 80; n++) cs += o1s[n] * S[n * 81 + tid];
        float diff = o1s[tid] - cs * (1.f / 80.f);
        dd[tid] = diff * diff;
    }
    __syncthreads();
    for (int idx = tid; idx < 6400; idx += 512){
        int n = idx / 80, m = idx - n * 80;
        ADJ[n * 90 + m] = __float2bfloat16(di_s[n] * S[m * 81 + n] * di_s[m]);
    }
    if (tid == 0){
        float s = 0.f;
        for (int m = 0; m < 80; m++) s += dd[m];
        lossp[b] = sqrtf(s);
    }
    for (int c0 = 0; c0 < 1024; c0 += 128){
        __syncthreads();
        {
            int cc = tid & 127, g = tid >> 7;
            const bf16* src = X2b + (size_t)b * 81920 + c0 + cc;
            #pragma unroll 5
            for (int m = g * 20; m < g * 20 + 20; m++)
                Btl[cc * 90 + m] = src[(size_t)m * 1024];
        }
        __syncthreads();
        f32x4 pacc[5];
        #pragma unroll
        for (int i = 0; i < 5; i++) pacc[i] = (f32x4){0.f, 0.f, 0.f, 0.f};
        #pragma unroll
        for (int ks = 0; ks < 3; ks++){
            int koff = (ks < 2) ? ks * 32 + hi * 8 : ((hi < 2) ? 64 + hi * 8 : 0);
            bool dead = (ks == 2) && (hi >= 2);
            bf16x8 bv = *(const bf16x8*)(Btl + (wave * 16 + l15) * 90 + koff);
            if (dead) bv = 0;
            #pragma unroll
            for (int i = 0; i < 5; i++){
                bf16x8 a = *(const bf16x8*)(ADJ + (i * 16 + l15) * 90 + koff);
                if (dead) a = 0;
                pacc[i] = __builtin_amdgcn_mfma_f32_16x16x32_bf16(a, bv, pacc[i], 0, 0, 0);
            }
        }
        #pragma unroll
        for (int i = 0; i < 5; i++){
            #pragma unroll
            for (int r = 0; r < 4; r++){
                int n = i * 16 + hi * 4 + r;
                int col = c0 + wave * 16 + l15;
                H[(size_t)b * 81920 + (size_t)n * 1024 + col] =
                    __float2bfloat16(leaky(pacc[i][r]));
            }
        }
    }
}

// ---------------- K11: loss = sum(lossp) ----------------
__global__ void k_lsum(const float* __restrict__ lossp, float* __restrict__ out_loss){
    float v = lossp[threadIdx.x];
    for (int off = 32; off; off >>= 1) v += __shfl_down(v, off);
    __shared__ float wsum[4];
    int lane = threadIdx.x & 63, w = threadIdx.x >> 6;
    if (lane == 0) wsum[w] = v;
    __syncthreads();
    if (threadIdx.x == 0) out_loss[0] = wsum[0] + wsum[1] + wsum[2] + wsum[3];
}

extern "C" void kernel_launch(void* const* d_in, const int* in_sizes, int n_in,
                              void* d_out, int out_size, void* d_ws, size_t ws_size,
                              hipStream_t stream) {
    const float* x     = (const float*)d_in[0];
    const float* out1  = (const float*)d_in[1];
    const float* A     = (const float*)d_in[2];
    const float* sw    = (const float*)d_in[3];
    const float* cgw   = (const float*)d_in[4];
    const float* gamma = (const float*)d_in[6];
    const float* beta  = (const float*)d_in[7];
    const float* ccw   = (const float*)d_in[8];
    const float* ccb   = (const float*)d_in[9];
    const float* dw    = (const float*)d_in[10];
    float* out = (float*)d_out;

    const size_t XN = (size_t)B_ * N_ * C_;   // 20,971,520
    char* p = (char*)d_ws;
    bf16*  Hbf  = (bf16*)p;   p += XN * 2;               // 42 MB
    bf16*  X2b  = (bf16*)p;   p += XN * 2;               // 42 MB
    bf16*  SWT  = (bf16*)p;   p += (size_t)C_ * C_ * 2;  // 2 MB
    bf16*  DWT  = (bf16*)p;   p += (size_t)C_ * CO_ * 2; // 2 MB
    bf16*  CCWB = (bf16*)p;   p += (size_t)N_ * 2048 * 2;
    bf16*  CGWB = (bf16*)p;   p += (size_t)C_ * C_ * 2;  // 2 MB
    bf16*  ADJS = (bf16*)p;   p += (size_t)80 * 88 * 2;
    bf16*  GLB0 = (bf16*)p;   p += (size_t)B_ * C_ * 2;
    float* GLB1P= (float*)p;  p += (size_t)4 * B_ * C_ * 4;   // 4 MB (K-parts)
    bf16*  GLB2 = (bf16*)p;   p += (size_t)B_ * C_ * 2;
    float* MU   = (float*)p;  p += C_ * 4;
    float* RSTD = (float*)p;  p += C_ * 4;
    float* LOSSP= (float*)p;  p += B_ * 4;

    k_convT2<<<dim3(32, 32, 2), 256, 0, stream>>>(sw, dw, SWT, DWT);
    k_cvt_all<<<(40960 + 262144) / 256, 256, 0, stream>>>(ccw, cgw, CCWB, CGWB);
    k_adj<<<1, 256, 0, stream>>>(A, ADJS);
    k_prop_static<<<dim3(B_, 8), 128, 0, stream>>>(x, ADJS, Hbf);
    k_gemm_mfma<0><<<1280, 256, 0, stream>>>(Hbf, SWT, x, X2b);
    k_pool<<<B_, 128, 0, stream>>>(X2b, GLB0);
    k_gemm_glb<<<64, 256, 0, stream>>>(GLB0, CGWB, GLB1P);
    k_bnstat<<<32, 256, 0, stream>>>(GLB1P, MU, RSTD);
    k_bnapply<<<(B_ * C_) / 256, 256, 0, stream>>>(GLB1P, MU, RSTD, gamma, beta, GLB2);
    k_dyn_prop<<<B_, 512, 0, stream>>>(X2b, CCWB, GLB2, ccb, out1, Hbf, LOSSP);
    k_lsum<<<1, 256, 0, stream>>>(LOSSP, out + (size_t)B_ * N_ * CO_);
    k_gemm_mfma<1><<<1280, 256, 0, stream>>>(Hbf, DWT, nullptr, out);
}